// Round 19
// baseline (24.692 us; speedup 1.0000x reference)
//
#include <hip/hip_runtime.h>

typedef __attribute__((ext_vector_type(8))) short bf16x8;
typedef __attribute__((ext_vector_type(4))) float f32x4;
typedef __attribute__((ext_vector_type(2))) float f32x2;
typedef __attribute__((ext_vector_type(4))) short short4v;

// Native cast -> v_cvt_pk_bf16_f32 on gfx950 (RNE).
__device__ __forceinline__ unsigned short f2bf(float x) {
    union { __bf16 h; unsigned short s; } u;
    u.h = (__bf16)x;
    return u.s;
}

__device__ __forceinline__ float bf2f(short s) {
    union { unsigned u; float f; } v;
    v.u = ((unsigned)(unsigned short)s) << 16;
    return v.f;
}

// K1: fused skinny GEMMs, R19 = K-split x2 across blocks for occupancy.
// R18 lesson: NO cross-kernel producer edges through d_ws under graph capture
// (wprep->gemm handoff gave stale-cache divergence on replays); W staging stays
// in-kernel. R15/R10 ledger: gemm ~10us warm (2x floor), all BW/ILP fixes
// neutral -> latency-bound at 2 blocks/CU (grid-limited). This round: grid
// 1024 (kchunk = bid>>9), each block does K=512; LDS = 32KB wpk + 8KB red =
// 40KB -> exactly 4 blocks/CU = 16 waves/CU (2x wave count).
// Partials: E16p[kchunk][2][4096][32] bf16; k3 sums the 2 chunks in fp32.
// Same k-slot bijection on A and B fragments -> k-permutation invariant.
__global__ __launch_bounds__(256) void gemm_fused(
    const float* __restrict__ hs, const float* __restrict__ seqW,
    const float* __restrict__ hidW, const float* __restrict__ cpw,
    unsigned short* __restrict__ E16 /* [2 kchunk][2][4096][32] bf16 */)
{
    __shared__ short wpk[16384];     // 2048 fragments x 16B = 32 KB
    __shared__ float red[4][16][32]; // 8 KB

    const int bid    = blockIdx.x;
    const int kchunk = bid >> 9;          // 0/1: K range [kchunk*512, +512)
    const int rest   = bid & 511;
    const bool hid   = rest >= 256;
    const int mt     = rest & 255;
    const int tid = threadIdx.x;
    const int wv  = tid >> 6;
    const int l   = tid & 63;
    const int l15 = l & 15;
    const int g   = l >> 4;
    const int m0  = mt * 16;
    const int mrow = m0 + l15;

    const float* __restrict__ W = hid ? hidW : seqW;
    size_t arow;
    if (hid) arow = ((size_t)(mrow >> 10) << 20) + (size_t)(mrow & 1023);
    else     arow = (size_t)mrow << 10;
    const int kbase = kchunk * 512 + wv * 128;   // wave's 128-K slice

    // ---- stage W chunk (32 rows x 512 k fp32) -> LDS bf16 fragments ----
    // frag(nt,kstep,g,l15) = nt*1024 + kstep*64 + g*16 + l15 (kstep in [0,16)),
    // 16B each, holds W[nt*16+l15][kchunk*512 + kstep*32 + g*8 .. +8].
    {
        const int rowg = tid >> 7;        // 0/1
        const int cth  = tid & 127;       // 0..127: k-offset cth*4 within chunk
        const int kstep = cth >> 3;
        const int gg    = (cth >> 1) & 3;
        const int half  = cth & 1;
        #pragma unroll 4
        for (int pass = 0; pass < 16; ++pass) {
            const int row = pass * 2 + rowg;
            f32x4 v = *(const f32x4*)(W + (size_t)row * 1024 + kchunk * 512 + cth * 4);
            short4v h4 = { (short)f2bf(v.x), (short)f2bf(v.y),
                           (short)f2bf(v.z), (short)f2bf(v.w) };
            const int frag = (row >> 4) * 1024 + kstep * 64 + gg * 16 + (row & 15);
            *(short4v*)&wpk[frag * 8 + half * 4] = h4;
        }
    }

    // ---- issue the wave's A-slice into registers (32 floats/lane) ----
    float a[32];
    if (hid) {
        const float* pa = hs + arow + (size_t)(kbase + g * 8) * 1024;
        #pragma unroll
        for (int ks = 0; ks < 4; ++ks)
            #pragma unroll
            for (int j = 0; j < 8; ++j)
                a[ks * 8 + j] = pa[(size_t)(ks * 32 + j) * 1024];
    } else {
        const f32x4* pa = (const f32x4*)(hs + arow + kbase + g * 8);
        #pragma unroll
        for (int ks = 0; ks < 4; ++ks) {
            f32x4 v0 = pa[ks * 8];
            f32x4 v1 = pa[ks * 8 + 1];
            a[ks*8+0]=v0.x; a[ks*8+1]=v0.y; a[ks*8+2]=v0.z; a[ks*8+3]=v0.w;
            a[ks*8+4]=v1.x; a[ks*8+5]=v1.y; a[ks*8+6]=v1.z; a[ks*8+7]=v1.w;
        }
    }

    __syncthreads();

    // ---- MFMA loop: 4 k-steps, B from LDS fragments ----
    f32x4 acc0 = {0.f,0.f,0.f,0.f}, acc1 = {0.f,0.f,0.f,0.f};
    #pragma unroll
    for (int ks = 0; ks < 4; ++ks) {
        const int kstep = wv * 4 + ks;
        bf16x8 af;
        #pragma unroll
        for (int j = 0; j < 8; ++j) af[j] = (short)f2bf(a[ks * 8 + j]);
        bf16x8 bf0 = *(const bf16x8*)&wpk[(kstep * 64 + g * 16 + l15) * 8];
        bf16x8 bf1 = *(const bf16x8*)&wpk[(1024 + kstep * 64 + g * 16 + l15) * 8];
        acc0 = __builtin_amdgcn_mfma_f32_16x16x32_bf16(af, bf0, acc0, 0, 0, 0);
        acc1 = __builtin_amdgcn_mfma_f32_16x16x32_bf16(af, bf1, acc1, 0, 0, 0);
    }

    // C/D layout (m89-verified): col = lane&15, row = (lane>>4)*4 + reg
    #pragma unroll
    for (int r = 0; r < 4; ++r) {
        red[wv][4 * g + r][l15]      = acc0[r];
        red[wv][4 * g + r][l15 + 16] = acc1[r];
    }
    __syncthreads();

    // Sum 4 wave-partials (this kchunk) -> fold cpw (seq) -> bf16 -> store.
    const int o = tid * 2;
    const float* rf = &red[0][0][0];
    float vx = rf[o]     + rf[512 + o]     + rf[1024 + o]     + rf[1536 + o];
    float vy = rf[o + 1] + rf[512 + o + 1] + rf[1024 + o + 1] + rf[1536 + o + 1];
    if (!hid) {
        f32x2 w = *(const f32x2*)(cpw + (o & 31));
        vx *= w.x; vy *= w.y;
    }
    unsigned pk = (unsigned)f2bf(vx) | ((unsigned)f2bf(vy) << 16);
    unsigned short* Eo = E16 + (size_t)kchunk * (2 * 4096 * 32)
                             + (hid ? (size_t)4096 * 32 : 0)
                             + (size_t)m0 * 32 + o;
    *(unsigned*)Eo = pk;
}

// Sum two bf16 fragments in fp32, re-round to bf16 (exact bf16->f32 via shift).
__device__ __forceinline__ bf16x8 sum2(bf16x8 x, bf16x8 y) {
    bf16x8 r;
    #pragma unroll
    for (int j = 0; j < 8; ++j)
        r[j] = (short)f2bf(bf2f(x[j]) + bf2f(y[j]));
    return r;
}

// K3: rank-32 GEMM via MFMA (R14 structure, nt stores); fragments are now the
// fp32 sum of the two K-chunk partials.
__global__ __launch_bounds__(256) void k3(const unsigned short* __restrict__ E16,
                                          float* __restrict__ out)
{
    const int tid = threadIdx.x;
    const int wv  = tid >> 6;
    const int l   = tid & 63;
    const int l15 = l & 15;
    const int g   = l >> 4;
    const int b   = blockIdx.z;
    const int s0  = blockIdx.y * 64 + wv * 16;
    const int h0  = blockIdx.x * 64;

    const size_t CH = (size_t)2 * 4096 * 32;   // shorts per kchunk slice
    const unsigned short* As0 = E16 + ((size_t)(b * 1024 + s0)) * 32;
    const unsigned short* Bh0 = E16 + (size_t)4096 * 32 + ((size_t)(b * 1024 + h0)) * 32;

    bf16x8 af = sum2(*(const bf16x8*)(As0 + (size_t)l15 * 32 + g * 8),
                     *(const bf16x8*)(As0 + CH + (size_t)l15 * 32 + g * 8));
    bf16x8 bfr[4];
    #pragma unroll
    for (int j = 0; j < 4; ++j)
        bfr[j] = sum2(*(const bf16x8*)(Bh0 + (size_t)(4 * l15 + j) * 32 + g * 8),
                      *(const bf16x8*)(Bh0 + CH + (size_t)(4 * l15 + j) * 32 + g * 8));

    const f32x4 zero = {0.f, 0.f, 0.f, 0.f};
    f32x4 acc[4];
    #pragma unroll
    for (int j = 0; j < 4; ++j)
        acc[j] = __builtin_amdgcn_mfma_f32_16x16x32_bf16(af, bfr[j], zero, 0, 0, 0);

    #pragma unroll
    for (int r = 0; r < 4; ++r) {
        f32x4 v = { acc[0][r], acc[1][r], acc[2][r], acc[3][r] };
        float* orow = out + ((size_t)(b * 1024 + s0 + 4 * g + r)) * 1024 + h0 + 4 * l15;
        __builtin_nontemporal_store(v, (f32x4*)orow);
    }
}

extern "C" void kernel_launch(void* const* d_in, const int* in_sizes, int n_in,
                              void* d_out, int out_size, void* d_ws, size_t ws_size,
                              hipStream_t stream) {
    const float* hs   = (const float*)d_in[0];
    // d_in[1] = all_indices: identically (n/H, n%H) -> computed implicitly
    const float* seqW = (const float*)d_in[2];
    const float* hidW = (const float*)d_in[3];
    const float* cpw  = (const float*)d_in[4];
    float* out = (float*)d_out;

    unsigned short* E16 = (unsigned short*)d_ws;   // [2][2][4096][32] bf16, 1 MB

    gemm_fused<<<1024, 256, 0, stream>>>(hs, seqW, hidW, cpw, E16);
    dim3 grid3(16, 16, 4);
    k3<<<grid3, 256, 0, stream>>>(E16, out);
}

// Round 20
// 20.730 us; speedup vs baseline: 1.1911x; 1.1911x over previous
//
#include <hip/hip_runtime.h>

typedef __attribute__((ext_vector_type(8))) short bf16x8;
typedef __attribute__((ext_vector_type(4))) float f32x4;
typedef __attribute__((ext_vector_type(2))) float f32x2;
typedef __attribute__((ext_vector_type(4))) short short4v;

// Native cast -> v_cvt_pk_bf16_f32 on gfx950 (RNE).
__device__ __forceinline__ unsigned short f2bf(float x) {
    union { __bf16 h; unsigned short s; } u;
    u.h = (__bf16)x;
    return u.s;
}

// R20 = R17 verbatim (best measured: 20.77us). R19's K-split x2 regressed
// (24.7); occupancy theory dead. Ledger: gemm ~10us, k3 ~3.5us, dispatches
// ~2us, fixed harness floor ~5us.
__global__ __launch_bounds__(256) void gemm_fused(
    const float* __restrict__ hs, const float* __restrict__ seqW,
    const float* __restrict__ hidW, const float* __restrict__ cpw,
    unsigned short* __restrict__ E16 /* [2][4096][32] bf16 */)
{
    __shared__ short wpk[32768];     // 4096 fragments x 16B = 64 KB
    __shared__ float red[4][16][32]; // 8 KB

    const int bid = blockIdx.x;
    const bool hid = bid >= 256;
    const int mt  = hid ? bid - 256 : bid;
    const int tid = threadIdx.x;
    const int wv  = tid >> 6;
    const int l   = tid & 63;
    const int l15 = l & 15;
    const int g   = l >> 4;
    const int m0  = mt * 16;
    const int mrow = m0 + l15;

    const float* __restrict__ W = hid ? hidW : seqW;
    size_t arow;
    if (hid) arow = ((size_t)(mrow >> 10) << 20) + (size_t)(mrow & 1023);
    else     arow = (size_t)mrow << 10;
    const int kbase = wv * 256;

    // ---- stage W (32 rows x 1024 k fp32) -> LDS bf16 fragments ----
    {
        const int kstep = tid >> 3;        // 0..31
        const int gg    = (tid >> 1) & 3;  // 0..3
        const int half  = tid & 1;         // k-offset 0 or 4 within fragment
        #pragma unroll 4
        for (int row = 0; row < 32; ++row) {
            f32x4 v = *(const f32x4*)(W + (size_t)row * 1024 + tid * 4);
            short4v h4 = { (short)f2bf(v.x), (short)f2bf(v.y),
                           (short)f2bf(v.z), (short)f2bf(v.w) };
            const int frag = (row >> 4) * 2048 + kstep * 64 + gg * 16 + (row & 15);
            *(short4v*)&wpk[frag * 8 + half * 4] = h4;
        }
    }

    // ---- issue the wave's ENTIRE A-slice into registers (64 floats/lane) ----
    float a[64];
    if (hid) {
        const float* pa = hs + arow + (size_t)(kbase + g * 8) * 1024;
        #pragma unroll
        for (int ks = 0; ks < 8; ++ks)
            #pragma unroll
            for (int j = 0; j < 8; ++j)
                a[ks * 8 + j] = pa[(size_t)(ks * 32 + j) * 1024];
    } else {
        const f32x4* pa = (const f32x4*)(hs + arow + kbase + g * 8);
        #pragma unroll
        for (int ks = 0; ks < 8; ++ks) {
            f32x4 v0 = pa[ks * 8];
            f32x4 v1 = pa[ks * 8 + 1];
            a[ks*8+0]=v0.x; a[ks*8+1]=v0.y; a[ks*8+2]=v0.z; a[ks*8+3]=v0.w;
            a[ks*8+4]=v1.x; a[ks*8+5]=v1.y; a[ks*8+6]=v1.z; a[ks*8+7]=v1.w;
        }
    }

    __syncthreads();

    // ---- MFMA loop: pure register cvt + LDS B-reads, zero global accesses ----
    f32x4 acc0 = {0.f,0.f,0.f,0.f}, acc1 = {0.f,0.f,0.f,0.f};
    #pragma unroll
    for (int ks = 0; ks < 8; ++ks) {
        const int kstep = wv * 8 + ks;
        bf16x8 af, bf0, bf1;
        #pragma unroll
        for (int j = 0; j < 8; ++j) af[j] = (short)f2bf(a[ks * 8 + j]);
        bf0 = *(const bf16x8*)&wpk[(kstep * 64 + g * 16 + l15) * 8];
        bf1 = *(const bf16x8*)&wpk[(2048 + kstep * 64 + g * 16 + l15) * 8];
        acc0 = __builtin_amdgcn_mfma_f32_16x16x32_bf16(af, bf0, acc0, 0, 0, 0);
        acc1 = __builtin_amdgcn_mfma_f32_16x16x32_bf16(af, bf1, acc1, 0, 0, 0);
    }

    // C/D layout (m89-verified): col = lane&15, row = (lane>>4)*4 + reg
    #pragma unroll
    for (int r = 0; r < 4; ++r) {
        red[wv][4 * g + r][l15]      = acc0[r];
        red[wv][4 * g + r][l15 + 16] = acc1[r];
    }
    __syncthreads();

    // Sum 4 wave-partials -> fold cpw (seq only) -> bf16 pack -> 4B store.
    const int o = tid * 2;
    const float* rf = &red[0][0][0];
    float vx = rf[o]     + rf[512 + o]     + rf[1024 + o]     + rf[1536 + o];
    float vy = rf[o + 1] + rf[512 + o + 1] + rf[1024 + o + 1] + rf[1536 + o + 1];
    if (!hid) {
        f32x2 w = *(const f32x2*)(cpw + (o & 31));
        vx *= w.x; vy *= w.y;
    }
    unsigned pk = (unsigned)f2bf(vx) | ((unsigned)f2bf(vy) << 16);
    unsigned short* Eo = E16 + (hid ? (size_t)4096 * 32 : 0) + (size_t)m0 * 32 + o;
    *(unsigned*)Eo = pk;
}

// K3: rank-32 GEMM via MFMA (R14 verbatim, nt stores). Measured ~3.5us.
__global__ __launch_bounds__(256) void k3(const unsigned short* __restrict__ E16,
                                          float* __restrict__ out)
{
    const int tid = threadIdx.x;
    const int wv  = tid >> 6;
    const int l   = tid & 63;
    const int l15 = l & 15;
    const int g   = l >> 4;
    const int b   = blockIdx.z;
    const int s0  = blockIdx.y * 64 + wv * 16;
    const int h0  = blockIdx.x * 64;

    const unsigned short* As = E16 + ((size_t)(b * 1024 + s0)) * 32;
    const unsigned short* Bh = E16 + (size_t)4096 * 32 + ((size_t)(b * 1024 + h0)) * 32;

    bf16x8 af = *(const bf16x8*)(As + (size_t)l15 * 32 + g * 8);
    bf16x8 bfr[4];
    #pragma unroll
    for (int j = 0; j < 4; ++j)
        bfr[j] = *(const bf16x8*)(Bh + (size_t)(4 * l15 + j) * 32 + g * 8);

    const f32x4 zero = {0.f, 0.f, 0.f, 0.f};
    f32x4 acc[4];
    #pragma unroll
    for (int j = 0; j < 4; ++j)
        acc[j] = __builtin_amdgcn_mfma_f32_16x16x32_bf16(af, bfr[j], zero, 0, 0, 0);

    #pragma unroll
    for (int r = 0; r < 4; ++r) {
        f32x4 v = { acc[0][r], acc[1][r], acc[2][r], acc[3][r] };
        float* orow = out + ((size_t)(b * 1024 + s0 + 4 * g + r)) * 1024 + h0 + 4 * l15;
        __builtin_nontemporal_store(v, (f32x4*)orow);
    }
}

extern "C" void kernel_launch(void* const* d_in, const int* in_sizes, int n_in,
                              void* d_out, int out_size, void* d_ws, size_t ws_size,
                              hipStream_t stream) {
    const float* hs   = (const float*)d_in[0];
    // d_in[1] = all_indices: identically (n/H, n%H) -> computed implicitly
    const float* seqW = (const float*)d_in[2];
    const float* hidW = (const float*)d_in[3];
    const float* cpw  = (const float*)d_in[4];
    float* out = (float*)d_out;

    unsigned short* E16 = (unsigned short*)d_ws;   // [2][4096][32] bf16, 512 KB

    gemm_fused<<<512, 256, 0, stream>>>(hs, seqW, hidW, cpw, E16);
    dim3 grid3(16, 16, 4);
    k3<<<grid3, 256, 0, stream>>>(E16, out);
}